// Round 9
// baseline (155.347 us; speedup 1.0000x reference)
//
#include <hip/hip_runtime.h>
#include <hip/hip_bf16.h>
#include <stdint.h>

typedef __attribute__((ext_vector_type(4))) float f32x4;
typedef __attribute__((ext_vector_type(8))) short short8;

#define NN 4096      // nodes
#define FIN 128
#define FHID 64
#define BATCH 32
#define NJ 2048      // BATCH * FHID

// ---------- helpers ----------
__device__ __forceinline__ unsigned short f2bf(float f) {
  unsigned u = __builtin_bit_cast(unsigned, f);
  u = (u + 0x7FFFu + ((u >> 16) & 1u)) >> 16;   // RNE
  return (unsigned short)u;
}
__device__ __forceinline__ float bf2f(unsigned short h) {
  unsigned u = ((unsigned)h) << 16;
  return __builtin_bit_cast(float, u);
}
__device__ __forceinline__ short8 pack8(f32x4 lo, f32x4 hi) {
  short8 w;
  #pragma unroll
  for (int j = 0; j < 4; ++j) {
    w[j]     = (short)f2bf(lo[j]);
    w[4 + j] = (short)f2bf(hi[j]);
  }
  return w;
}
__device__ __forceinline__ void gload_lds16(const void* g, void* l) {
  __builtin_amdgcn_global_load_lds(
      (const __attribute__((address_space(1))) unsigned int*)g,
      (__attribute__((address_space(3))) unsigned int*)l, 16, 0, 0);
}

// ---------- K1: St[b*64+h][m] = sum_f x[b][m][f] * W1[f][h]  (bf16 out) ----------
// MFMA version: x cast to bf16 in regs, W1^T (bf16, padded) in LDS.
__global__ __launch_bounds__(256) void k_support(const float* __restrict__ x,
                                                 const float* __restrict__ W1,
                                                 unsigned short* __restrict__ St) {
  __shared__ unsigned short W1t[FHID * 136];              // [h][f], pad 136
  __shared__ __align__(16) unsigned short T[FHID * 128];  // [h][m_loc]
  const int tid = threadIdx.x;
  for (int i = tid; i < FIN * FHID; i += 256) {
    int f = i >> 6, h = i & 63;
    W1t[h * 136 + f] = f2bf(W1[i]);
  }
  __syncthreads();

  const int bb = blockIdx.x >> 5;
  const int m0 = (blockIdx.x & 31) * 128;
  const int lane = tid & 63, wv = tid >> 6;
  const int fr = lane & 15, fq = lane >> 4;

  short8 bfr[4][4];
  #pragma unroll
  for (int ni = 0; ni < 4; ++ni)
    #pragma unroll
    for (int ks = 0; ks < 4; ++ks)
      bfr[ni][ks] = *(const short8*)&W1t[(ni * 16 + fr) * 136 + ks * 32 + fq * 8];

  const float* xr0 = x + ((size_t)bb * NN + m0 + wv * 32 + fr) * FIN;
  const float* xr1 = xr0 + (size_t)16 * FIN;

  f32x4 z = {0.f, 0.f, 0.f, 0.f};
  f32x4 acc[2][4];
  #pragma unroll
  for (int mf = 0; mf < 2; ++mf)
    #pragma unroll
    for (int ni = 0; ni < 4; ++ni) acc[mf][ni] = z;

  #pragma unroll
  for (int ks = 0; ks < 4; ++ks) {
    #pragma unroll
    for (int mf = 0; mf < 2; ++mf) {
      const float* src = (mf ? xr1 : xr0) + ks * 32 + fq * 8;
      f32x4 lo = *(const f32x4*)src;
      f32x4 hi = *(const f32x4*)(src + 4);
      short8 a;
      #pragma unroll
      for (int j = 0; j < 4; ++j) { a[j] = (short)f2bf(lo[j]); a[4 + j] = (short)f2bf(hi[j]); }
      #pragma unroll
      for (int ni = 0; ni < 4; ++ni)
        acc[mf][ni] = __builtin_amdgcn_mfma_f32_16x16x32_bf16(a, bfr[ni][ks], acc[mf][ni], 0, 0, 0);
    }
  }

  const int cr = (lane >> 4) * 4, cc = lane & 15;
  #pragma unroll
  for (int mf = 0; mf < 2; ++mf)
    #pragma unroll
    for (int ni = 0; ni < 4; ++ni) {
      ushort4 o;
      o.x = f2bf(acc[mf][ni][0]); o.y = f2bf(acc[mf][ni][1]);
      o.z = f2bf(acc[mf][ni][2]); o.w = f2bf(acc[mf][ni][3]);
      *(ushort4*)&T[(ni * 16 + cc) * 128 + wv * 32 + mf * 16 + cr] = o;
    }
  __syncthreads();
  for (int u = tid; u < FHID * 16; u += 256) {
    int row = u >> 4, ch = u & 15;
    *(short8*)(St + (size_t)(bb * FHID + row) * NN + m0 + ch * 8) =
        *(const short8*)&T[row * 128 + ch * 8];
  }
}

// ---------- K2: H = relu(adj_f32 @ St^T + b1) ----------
// R5-exact schedule (BM=256 x BN=128, BK=64, 8 waves 4M x 2N, per-wave 64x64,
// dbuf LDS 96 KB, 4 single-barrier phases/K-tile, reg-dbuf bvA) with the
// fp32->bf16 conversion of A FUSED into staging: A loads fp32->regs at P0,
// cvt+ds_write chunks 0,1 at P1 and 2,3 at P3 (same dead-after-read guards
// as R5's gload placements); B stays global_load_lds. Correctness of B(t+1)
// landing is forced by P1's compiler vmcnt wait (FIFO: B older than A-regs);
// VMW(5) at P3 is the explicit guard. XOR-swizzle via pre-swizzled source.
#define VMW(N)  asm volatile("s_waitcnt vmcnt(" #N ")" ::: "memory")
#define LGKM0   asm volatile("s_waitcnt lgkmcnt(0)" ::: "memory")
#define BAR     __builtin_amdgcn_s_barrier()

__global__ __launch_bounds__(512, 1) void k_gemm(const float* __restrict__ Af,
                                                 const unsigned short* __restrict__ Bt,
                                                 const float* __restrict__ b1,
                                                 unsigned short* __restrict__ H) {
  __shared__ __align__(16) unsigned short As[2 * 16384];  // A: 256x64 dbuf, 64 KB
  __shared__ __align__(16) unsigned short Bs[2 * 8192];   // B: 128x64 dbuf, 32 KB

  const int tid  = threadIdx.x;
  const int lane = tid & 63;
  const int wv   = tid >> 6;
  const int wm   = wv >> 1;          // 0..3 (M)
  const int wn   = wv & 1;           // 0..1 (N)
  const int bm   = blockIdx.x * 256;
  const int bn   = blockIdx.y * 128;
  const int fr   = lane & 15;
  const int fq   = lane >> 4;

  // fragment LDS ushort offsets (buffer-relative)
  int offA[2][2][2], offB[4][2];
  #pragma unroll
  for (int h = 0; h < 2; ++h)
    #pragma unroll
    for (int m2 = 0; m2 < 2; ++m2) {
      int row = wm * 32 + h * 128 + m2 * 16 + fr;
      #pragma unroll
      for (int ks = 0; ks < 2; ++ks)
        offA[h][m2][ks] = row * 64 + ((((ks << 6) + (fq << 4)) ^ ((row & 7) << 4)) >> 1);
    }
  #pragma unroll
  for (int ni = 0; ni < 4; ++ni) {
    int row = wn * 32 + (ni & 1) * 16 + (ni >> 1) * 64 + fr;
    #pragma unroll
    for (int ks = 0; ks < 2; ++ks)
      offB[ni][ks] = row * 64 + ((((ks << 6) + (fq << 4)) ^ ((row & 7) << 4)) >> 1);
  }

  // staging addresses (pre-swizzled global source, linear LDS dest)
  const int srow  = tid >> 3;
  const int scolE = ((((tid & 7) << 4) ^ ((srow & 7) << 4)) >> 1);  // element idx
  const float* gAf0 = Af + (size_t)(bm +   0 + srow) * NN + scolE;
  const float* gAf1 = Af + (size_t)(bm +  64 + srow) * NN + scolE;
  const float* gAf2 = Af + (size_t)(bm + 128 + srow) * NN + scolE;
  const float* gAf3 = Af + (size_t)(bm + 192 + srow) * NN + scolE;
  const unsigned short* gB0 = Bt + (size_t)(bn +  0 + srow) * NN + scolE;
  const unsigned short* gB1 = Bt + (size_t)(bn + 64 + srow) * NN + scolE;
  const int ld = tid * 8;   // ushort offset of this thread's 16B slot

  f32x4 z = {0.f, 0.f, 0.f, 0.f};
  f32x4 acc[4][4];
  #pragma unroll
  for (int i = 0; i < 4; ++i)
    #pragma unroll
    for (int j = 0; j < 4; ++j) acc[i][j] = z;

  short8 av0[2][2], av1[2][2], bvB[2][2], bvA0[2][2], bvA1[2][2];
  f32x4 a0lo, a0hi, a1lo, a1hi, a2lo, a2hi, a3lo, a3hi;

#define RD_AVA(Ac)                                                             \
    _Pragma("unroll") for (int m2 = 0; m2 < 2; ++m2)                           \
    _Pragma("unroll") for (int ks = 0; ks < 2; ++ks)                           \
      av0[m2][ks] = *(const short8*)((Ac) + offA[0][m2][ks]);
#define RD_AVB(Ac)                                                             \
    _Pragma("unroll") for (int m2 = 0; m2 < 2; ++m2)                           \
    _Pragma("unroll") for (int ks = 0; ks < 2; ++ks)                           \
      av1[m2][ks] = *(const short8*)((Ac) + offA[1][m2][ks]);
#define RD_BV(DST, Bb, P)                                                      \
    _Pragma("unroll") for (int n2 = 0; n2 < 2; ++n2)                           \
    _Pragma("unroll") for (int ks = 0; ks < 2; ++ks)                           \
      DST[n2][ks] = *(const short8*)((Bb) + offB[2 * (P) + n2][ks]);
#define MFMA8(MP, AV, BV, NP)                                                  \
    __builtin_amdgcn_s_setprio(1);                                             \
    _Pragma("unroll") for (int m2 = 0; m2 < 2; ++m2)                           \
    _Pragma("unroll") for (int n2 = 0; n2 < 2; ++n2)                           \
    _Pragma("unroll") for (int ks = 0; ks < 2; ++ks)                           \
      acc[2 * (MP) + m2][2 * (NP) + n2] = __builtin_amdgcn_mfma_f32_16x16x32_bf16( \
          AV[m2][ks], BV[n2][ks], acc[2 * (MP) + m2][2 * (NP) + n2], 0, 0, 0); \
    __builtin_amdgcn_s_setprio(0);
#define GLD_A(KQ)                                                              \
    a0lo = *(const f32x4*)(gAf0 + (KQ)); a0hi = *(const f32x4*)(gAf0 + (KQ) + 4); \
    a1lo = *(const f32x4*)(gAf1 + (KQ)); a1hi = *(const f32x4*)(gAf1 + (KQ) + 4); \
    a2lo = *(const f32x4*)(gAf2 + (KQ)); a2hi = *(const f32x4*)(gAf2 + (KQ) + 4); \
    a3lo = *(const f32x4*)(gAf3 + (KQ)); a3hi = *(const f32x4*)(gAf3 + (KQ) + 4);
#define DSW_A01(BUF)                                                           \
    *(short8*)(As + (BUF) * 16384 + 0 * 4096 + ld) = pack8(a0lo, a0hi);        \
    *(short8*)(As + (BUF) * 16384 + 1 * 4096 + ld) = pack8(a1lo, a1hi);
#define DSW_A23(BUF)                                                           \
    *(short8*)(As + (BUF) * 16384 + 2 * 4096 + ld) = pack8(a2lo, a2hi);        \
    *(short8*)(As + (BUF) * 16384 + 3 * 4096 + ld) = pack8(a3lo, a3hi);
#define SG_B0(KO, BUF) gload_lds16(gB0 + (KO), Bs + (BUF) * 8192 + 0 * 4096 + ld);
#define SG_B1(KO, BUF) gload_lds16(gB1 + (KO), Bs + (BUF) * 8192 + 1 * 4096 + ld);

// One K-tile, 4 single-barrier phases (R5 guards):
// P0: reads Q00 ops; issue 8 fp32 A loads (t+2).
// P1: read bvB; cvt+ds_write A chunks 0,1 (t+2)  [A-h0 read at P0].
// P2: read av1; stage B-h1 (t+2)                  [B-h1 read at P1].
// P3: VMW; cvt+ds_write A chunks 2,3 + stage B-h0 (t+2); read bvA(t+1).
#define TILE(CUR, BVA_C, BVA_N, KQ, DOS, VMWOP) {                              \
    const unsigned short* Ac = As + (CUR) * 16384;                             \
    const unsigned short* Bc = Bs + (CUR) * 8192;                              \
    const unsigned short* Bn = Bs + (1 - (CUR)) * 8192;                        \
    /* P0 */                                                                   \
    RD_AVA(Ac)                                                                 \
    if (DOS) { GLD_A(KQ) }                                                     \
    BAR; LGKM0;                                                                \
    MFMA8(0, av0, BVA_C, 0)                                                    \
    /* P1 */                                                                   \
    RD_BV(bvB, Bc, 1)                                                          \
    if (DOS) { DSW_A01(CUR) }                                                  \
    BAR; LGKM0;                                                                \
    MFMA8(0, av0, bvB, 1)                                                      \
    /* P2 */                                                                   \
    RD_AVB(Ac)                                                                 \
    if (DOS) { SG_B1(KQ, CUR) }                                                \
    BAR; LGKM0;                                                                \
    MFMA8(1, av1, bvB, 1)                                                      \
    /* P3 */                                                                   \
    VMWOP;                                                                     \
    if (DOS) { DSW_A23(CUR) SG_B0(KQ, CUR) }                                   \
    BAR;                                                                       \
    RD_BV(BVA_N, Bn, 0)                                                        \
    MFMA8(1, av1, BVA_C, 0)                                                    \
  }

  // ---- prologue: stage tiles 0 (buf0) and 1 (buf1) ----
  SG_B0(0, 0) SG_B1(0, 0) SG_B0(64, 1) SG_B1(64, 1)
  GLD_A(0)
  DSW_A01(0) DSW_A23(0)
  GLD_A(64)
  DSW_A01(1) DSW_A23(1)
  VMW(0); LGKM0;
  BAR;
  RD_BV(bvA0, Bs, 0)      // prime bvA for tile 0 (waited at tile0 P0 LGKM0)

  // ---- main loop: 31 macro-iters = tiles 0..61 (stage t+2) ----
  int kq = 128;
  #pragma unroll 1
  for (int g = 0; g < 31; ++g) {
    TILE(0, bvA0, bvA1, kq,      1, VMW(5))
    TILE(1, bvA1, bvA0, kq + 64, 1, VMW(5))
    kq += 128;
  }
  // ---- tile 62 (buf0): no staging; drain B(63) for tile 63 ----
  TILE(0, bvA0, bvA1, 0, 0, VMW(0))
  // ---- tile 63 (buf1): last ----
  {
    const unsigned short* Ac = As + 16384;
    const unsigned short* Bc = Bs + 8192;
    RD_AVA(Ac)
    BAR; LGKM0;
    MFMA8(0, av0, bvA1, 0)
    RD_BV(bvB, Bc, 1)
    BAR; LGKM0;
    MFMA8(0, av0, bvB, 1)
    RD_AVB(Ac)
    BAR; LGKM0;
    MFMA8(1, av1, bvB, 1)
    MFMA8(1, av1, bvA1, 0)
  }
#undef RD_AVA
#undef RD_AVB
#undef RD_BV
#undef MFMA8
#undef GLD_A
#undef DSW_A01
#undef DSW_A23
#undef SG_B0
#undef SG_B1
#undef TILE

  // ---- epilogue: bias + relu, store bf16 ----
  const int cr = (lane >> 4) * 4;
  const int cc = lane & 15;
  #pragma unroll
  for (int ni = 0; ni < 4; ++ni) {
    int col = bn + wn * 32 + (ni & 1) * 16 + (ni >> 1) * 64 + cc;
    float bias = b1[col & 63];
    #pragma unroll
    for (int mi = 0; mi < 4; ++mi) {
      int rowb = bm + wm * 32 + (mi & 1) * 16 + (mi >> 1) * 128 + cr;
      #pragma unroll
      for (int r = 0; r < 4; ++r) {
        float v = acc[mi][ni][r] + bias;
        v = v > 0.f ? v : 0.f;
        H[(long)(rowb + r) * NJ + col] = f2bf(v);
      }
    }
  }
}

// ---------- K3: partial[b][c][h] = sum_{n in chunk c} adj[q_b][n] * H[n][b*64+h] ----------
__global__ __launch_bounds__(256) void k_agg(const float* __restrict__ adj,
                                             const int* __restrict__ q_ids,
                                             const unsigned short* __restrict__ H,
                                             float* __restrict__ partial) {
  int b = blockIdx.x;        // 0..31
  int c = blockIdx.y;        // 0..15
  int h = threadIdx.x & 63;
  int w = threadIdx.x >> 6;
  int q = q_ids[b];
  const float* arow = adj + (long)q * NN;
  int j = b * FHID + h;
  float s = 0.f;
  int n0 = c * 256;
  for (int n = n0 + w; n < n0 + 256; n += 4)
    s += arow[n] * bf2f(H[(long)n * NJ + j]);
  __shared__ float red[4][64];
  red[w][h] = s;
  __syncthreads();
  if (w == 0)
    partial[((b << 4) + c) * 64 + h] = red[0][h] + red[1][h] + red[2][h] + red[3][h];
}

// ---------- K4: out[b][l] = sum_h agg[b][h]*W2[h][l] + b2[l] ----------
__global__ __launch_bounds__(1024) void k_out(const float* __restrict__ partial,
                                              const float* __restrict__ W2,
                                              const float* __restrict__ b2,
                                              float* __restrict__ out) {
  __shared__ float aggs[BATCH * FHID];   // 2048
  int t = threadIdx.x;
  for (int idx = t; idx < BATCH * FHID; idx += 1024) {
    int base = (idx >> 6) * (16 * 64) + (idx & 63);
    float s = 0.f;
    #pragma unroll
    for (int c = 0; c < 16; ++c) s += partial[base + c * 64];
    aggs[idx] = s;
  }
  __syncthreads();
  int b = t >> 5, l = t & 31;
  float o = b2[l];
  #pragma unroll
  for (int h = 0; h < FHID; ++h) o += aggs[b * FHID + h] * W2[h * 32 + l];
  out[b * 32 + l] = o;
}

extern "C" void kernel_launch(void* const* d_in, const int* in_sizes, int n_in,
                              void* d_out, int out_size, void* d_ws, size_t ws_size,
                              hipStream_t stream) {
  const float* x   = (const float*)d_in[0];
  const int*   q   = (const int*)d_in[1];
  const float* adj = (const float*)d_in[2];
  const float* W1  = (const float*)d_in[3];
  const float* b1  = (const float*)d_in[4];
  const float* W2  = (const float*)d_in[5];
  const float* b2  = (const float*)d_in[6];
  float* out = (float*)d_out;

  char* ws = (char*)d_ws;
  unsigned short* St     = (unsigned short*)ws;                               // 16 MB
  unsigned short* H      = (unsigned short*)(ws + (size_t)16 * 1024 * 1024);  // 16 MB
  float*          partial= (float*)(ws + (size_t)32 * 1024 * 1024);           // 128 KB

  // K1: support^T via MFMA
  k_support<<<1024, 256, 0, stream>>>(x, W1, St);
  // K2: big GEMM + bias + relu (fp32 A converted in-staging; no k_convert)
  dim3 g2(NN / 256, NJ / 128);
  k_gemm<<<g2, 512, 0, stream>>>(adj, St, b1, H);
  // K3: row-gather aggregation
  dim3 g3(BATCH, 16);
  k_agg<<<g3, 256, 0, stream>>>(adj, q, H, partial);
  // K4: final tiny GEMM
  k_out<<<1, 1024, 0, stream>>>(partial, W2, b2, out);
}

// Round 10
// 101.137 us; speedup vs baseline: 1.5360x; 1.5360x over previous
//
#include <hip/hip_runtime.h>
#include <hip/hip_bf16.h>
#include <stdint.h>

typedef __attribute__((ext_vector_type(4))) float f32x4;
typedef __attribute__((ext_vector_type(8))) short short8;

#define NN 4096      // nodes
#define FIN 128
#define FHID 64
#define BATCH 32
#define NJ 2048      // BATCH * FHID

// ---------- helpers ----------
__device__ __forceinline__ unsigned short f2bf(float f) {
  unsigned u = __builtin_bit_cast(unsigned, f);
  u = (u + 0x7FFFu + ((u >> 16) & 1u)) >> 16;   // RNE
  return (unsigned short)u;
}
__device__ __forceinline__ float bf2f(unsigned short h) {
  unsigned u = ((unsigned)h) << 16;
  return __builtin_bit_cast(float, u);
}
__device__ __forceinline__ void gload_lds16(const void* g, void* l) {
  __builtin_amdgcn_global_load_lds(
      (const __attribute__((address_space(1))) unsigned int*)g,
      (__attribute__((address_space(3))) unsigned int*)l, 16, 0, 0);
}

// ---------- K0: adj fp32 -> bf16 ----------
__global__ __launch_bounds__(256) void k_convert(const float* __restrict__ adj,
                                                 unsigned short* __restrict__ adjb) {
  long i = (long)blockIdx.x * 256 + threadIdx.x;
  const f32x4* in = (const f32x4*)adj;
  f32x4 v = in[i];
  ushort4 o;
  o.x = f2bf(v.x); o.y = f2bf(v.y); o.z = f2bf(v.z); o.w = f2bf(v.w);
  *(ushort4*)(adjb + i * 4) = o;
}

// ---------- K1: St[b*64+h][m] = sum_f x[b][m][f] * W1[f][h]  (bf16 out) ----------
__global__ __launch_bounds__(256) void k_support(const float* __restrict__ x,
                                                 const float* __restrict__ W1,
                                                 unsigned short* __restrict__ St) {
  __shared__ unsigned short W1t[FHID * 136];              // [h][f], pad 136
  __shared__ __align__(16) unsigned short T[FHID * 128];  // [h][m_loc]
  const int tid = threadIdx.x;
  for (int i = tid; i < FIN * FHID; i += 256) {
    int f = i >> 6, h = i & 63;
    W1t[h * 136 + f] = f2bf(W1[i]);
  }
  __syncthreads();

  const int bb = blockIdx.x >> 5;
  const int m0 = (blockIdx.x & 31) * 128;
  const int lane = tid & 63, wv = tid >> 6;
  const int fr = lane & 15, fq = lane >> 4;

  short8 bfr[4][4];
  #pragma unroll
  for (int ni = 0; ni < 4; ++ni)
    #pragma unroll
    for (int ks = 0; ks < 4; ++ks)
      bfr[ni][ks] = *(const short8*)&W1t[(ni * 16 + fr) * 136 + ks * 32 + fq * 8];

  const float* xr0 = x + ((size_t)bb * NN + m0 + wv * 32 + fr) * FIN;
  const float* xr1 = xr0 + (size_t)16 * FIN;

  f32x4 z = {0.f, 0.f, 0.f, 0.f};
  f32x4 acc[2][4];
  #pragma unroll
  for (int mf = 0; mf < 2; ++mf)
    #pragma unroll
    for (int ni = 0; ni < 4; ++ni) acc[mf][ni] = z;

  #pragma unroll
  for (int ks = 0; ks < 4; ++ks) {
    #pragma unroll
    for (int mf = 0; mf < 2; ++mf) {
      const float* src = (mf ? xr1 : xr0) + ks * 32 + fq * 8;
      f32x4 lo = *(const f32x4*)src;
      f32x4 hi = *(const f32x4*)(src + 4);
      short8 a;
      #pragma unroll
      for (int j = 0; j < 4; ++j) { a[j] = (short)f2bf(lo[j]); a[4 + j] = (short)f2bf(hi[j]); }
      #pragma unroll
      for (int ni = 0; ni < 4; ++ni)
        acc[mf][ni] = __builtin_amdgcn_mfma_f32_16x16x32_bf16(a, bfr[ni][ks], acc[mf][ni], 0, 0, 0);
    }
  }

  const int cr = (lane >> 4) * 4, cc = lane & 15;
  #pragma unroll
  for (int mf = 0; mf < 2; ++mf)
    #pragma unroll
    for (int ni = 0; ni < 4; ++ni) {
      ushort4 o;
      o.x = f2bf(acc[mf][ni][0]); o.y = f2bf(acc[mf][ni][1]);
      o.z = f2bf(acc[mf][ni][2]); o.w = f2bf(acc[mf][ni][3]);
      *(ushort4*)&T[(ni * 16 + cc) * 128 + wv * 32 + mf * 16 + cr] = o;
    }
  __syncthreads();
  for (int u = tid; u < FHID * 16; u += 256) {
    int row = u >> 4, ch = u & 15;
    *(short8*)(St + (size_t)(bb * FHID + row) * NN + m0 + ch * 8) =
        *(const short8*)&T[row * 128 + ch * 8];
  }
}

// ---------- K2: fused GEMM + bias + relu + row-weighted aggregation ----------
// K-loop: R5-exact schedule (benched 68.7 us): BM=256 x BN=128, BK=64,
// 8 waves 4M x 2N, per-wave 64x64, dbuf LDS 96 KB, 4 single-barrier
// phases/K-tile, reg-dbuf bvA, one vmcnt(3)/tile, XOR-swizzle via
// pre-swizzled global source.
// Epilogue: instead of storing H, weight relu(acc+bias) by adj[q_b][row]
// and reduce over the block's 256 rows -> partial[rowblock][col] (fp32).
#define VMW(N)  asm volatile("s_waitcnt vmcnt(" #N ")" ::: "memory")
#define LGKM0   asm volatile("s_waitcnt lgkmcnt(0)" ::: "memory")
#define BAR     __builtin_amdgcn_s_barrier()

__global__ __launch_bounds__(512, 1) void k_gemm(const unsigned short* __restrict__ A,
                                                 const unsigned short* __restrict__ Bt,
                                                 const float* __restrict__ b1,
                                                 const float* __restrict__ adj,
                                                 const int* __restrict__ q_ids,
                                                 float* __restrict__ partial) {
  __shared__ __align__(16) unsigned short As[2 * 16384];  // A: 256x64 dbuf, 64 KB
  __shared__ __align__(16) unsigned short Bs[2 * 8192];   // B: 128x64 dbuf, 32 KB
  __shared__ float adjw[2][256];                          // 2 KB (epilogue)
  __shared__ float red[8][64];                            // 2 KB (epilogue)

  const int tid  = threadIdx.x;
  const int lane = tid & 63;
  const int wv   = tid >> 6;
  const int wm   = wv >> 1;          // 0..3 (M)
  const int wn   = wv & 1;           // 0..1 (N)
  const int bm   = blockIdx.x * 256;
  const int bn   = blockIdx.y * 128;
  const int fr   = lane & 15;
  const int fq   = lane >> 4;

  // fragment LDS ushort offsets (buffer-relative)
  int offA[2][2][2], offB[4][2];
  #pragma unroll
  for (int h = 0; h < 2; ++h)
    #pragma unroll
    for (int m2 = 0; m2 < 2; ++m2) {
      int row = wm * 32 + h * 128 + m2 * 16 + fr;
      #pragma unroll
      for (int ks = 0; ks < 2; ++ks)
        offA[h][m2][ks] = row * 64 + ((((ks << 6) + (fq << 4)) ^ ((row & 7) << 4)) >> 1);
    }
  #pragma unroll
  for (int ni = 0; ni < 4; ++ni) {
    int row = wn * 32 + (ni & 1) * 16 + (ni >> 1) * 64 + fr;
    #pragma unroll
    for (int ks = 0; ks < 2; ++ks)
      offB[ni][ks] = row * 64 + ((((ks << 6) + (fq << 4)) ^ ((row & 7) << 4)) >> 1);
  }

  // staging addresses (pre-swizzled global source, linear LDS dest)
  const int srow = tid >> 3;
  const int scol = ((((tid & 7) << 4) ^ ((srow & 7) << 4)) >> 1);
  const unsigned short* gA00 = A + (size_t)(bm +   0 + srow) * NN + scol;
  const unsigned short* gA01 = A + (size_t)(bm +  64 + srow) * NN + scol;
  const unsigned short* gA10 = A + (size_t)(bm + 128 + srow) * NN + scol;
  const unsigned short* gA11 = A + (size_t)(bm + 192 + srow) * NN + scol;
  const unsigned short* gB0  = Bt + (size_t)(bn +  0 + srow) * NN + scol;
  const unsigned short* gB1  = Bt + (size_t)(bn + 64 + srow) * NN + scol;
  const int ld = tid * 8;

  f32x4 z = {0.f, 0.f, 0.f, 0.f};
  f32x4 acc[4][4];
  #pragma unroll
  for (int i = 0; i < 4; ++i)
    #pragma unroll
    for (int j = 0; j < 4; ++j) acc[i][j] = z;

  short8 av0[2][2], av1[2][2], bvB[2][2], bvA0[2][2], bvA1[2][2];

#define RD_AVA(Ac)                                                             \
    _Pragma("unroll") for (int m2 = 0; m2 < 2; ++m2)                           \
    _Pragma("unroll") for (int ks = 0; ks < 2; ++ks)                           \
      av0[m2][ks] = *(const short8*)((Ac) + offA[0][m2][ks]);
#define RD_AVB(Ac)                                                             \
    _Pragma("unroll") for (int m2 = 0; m2 < 2; ++m2)                           \
    _Pragma("unroll") for (int ks = 0; ks < 2; ++ks)                           \
      av1[m2][ks] = *(const short8*)((Ac) + offA[1][m2][ks]);
#define RD_BV(DST, Bb, P)                                                      \
    _Pragma("unroll") for (int n2 = 0; n2 < 2; ++n2)                           \
    _Pragma("unroll") for (int ks = 0; ks < 2; ++ks)                           \
      DST[n2][ks] = *(const short8*)((Bb) + offB[2 * (P) + n2][ks]);
#define MFMA8(MP, AV, BV, NP)                                                  \
    __builtin_amdgcn_s_setprio(1);                                             \
    _Pragma("unroll") for (int m2 = 0; m2 < 2; ++m2)                           \
    _Pragma("unroll") for (int n2 = 0; n2 < 2; ++n2)                           \
    _Pragma("unroll") for (int ks = 0; ks < 2; ++ks)                           \
      acc[2 * (MP) + m2][2 * (NP) + n2] = __builtin_amdgcn_mfma_f32_16x16x32_bf16( \
          AV[m2][ks], BV[n2][ks], acc[2 * (MP) + m2][2 * (NP) + n2], 0, 0, 0); \
    __builtin_amdgcn_s_setprio(0);

#define TILE(CUR, BVA_C, BVA_N, KQ, DOS, VMWOP) {                              \
    const unsigned short* Ac = As + (CUR) * 16384;                             \
    const unsigned short* Bc = Bs + (CUR) * 8192;                              \
    const unsigned short* Bn = Bs + (1 - (CUR)) * 8192;                        \
    /* P0: Q(0,0) */                                                           \
    RD_AVA(Ac)                                                                 \
    BAR; LGKM0;                                                                \
    MFMA8(0, av0, BVA_C, 0)                                                    \
    /* P1: Q(0,1); stage A-h0(t+2) */                                          \
    RD_BV(bvB, Bc, 1)                                                          \
    if (DOS) {                                                                 \
      gload_lds16(gA00 + (KQ), As + (CUR) * 16384 + 0 * 4096 + ld);            \
      gload_lds16(gA01 + (KQ), As + (CUR) * 16384 + 1 * 4096 + ld);            \
    }                                                                          \
    BAR; LGKM0;                                                                \
    MFMA8(0, av0, bvB, 1)                                                      \
    /* P2: Q(1,1); stage B-h1(t+2) */                                          \
    RD_AVB(Ac)                                                                 \
    if (DOS) {                                                                 \
      gload_lds16(gB1 + (KQ), Bs + (CUR) * 8192 + 1 * 4096 + ld);              \
    }                                                                          \
    BAR; LGKM0;                                                                \
    MFMA8(1, av1, bvB, 1)                                                      \
    /* P3: Q(1,0); vmcnt; stage A-h1,B-h0(t+2); read bvA(t+1) post-barrier */  \
    VMWOP;                                                                     \
    if (DOS) {                                                                 \
      gload_lds16(gA10 + (KQ), As + (CUR) * 16384 + 2 * 4096 + ld);            \
      gload_lds16(gA11 + (KQ), As + (CUR) * 16384 + 3 * 4096 + ld);            \
      gload_lds16(gB0  + (KQ), Bs + (CUR) * 8192 + 0 * 4096 + ld);             \
    }                                                                          \
    BAR;                                                                       \
    RD_BV(BVA_N, Bn, 0)                                                        \
    MFMA8(1, av1, BVA_C, 0)                                                    \
  }

  // ---- prologue: stage tile0 -> buf0, tile1 -> buf1 ----
  gload_lds16(gB0,       Bs + 0 * 4096 + ld);
  gload_lds16(gB1,       Bs + 1 * 4096 + ld);
  gload_lds16(gA00,      As + 0 * 4096 + ld);
  gload_lds16(gA01,      As + 1 * 4096 + ld);
  gload_lds16(gA10,      As + 2 * 4096 + ld);
  gload_lds16(gA11,      As + 3 * 4096 + ld);
  gload_lds16(gB0  + 64, Bs + 8192 + 0 * 4096 + ld);
  gload_lds16(gB1  + 64, Bs + 8192 + 1 * 4096 + ld);
  gload_lds16(gA00 + 64, As + 16384 + 0 * 4096 + ld);
  gload_lds16(gA01 + 64, As + 16384 + 1 * 4096 + ld);
  gload_lds16(gA10 + 64, As + 16384 + 2 * 4096 + ld);
  gload_lds16(gA11 + 64, As + 16384 + 3 * 4096 + ld);
  VMW(6);                 // own tile-0 loads drained
  BAR;                    // => all waves' tile-0 loads visible
  RD_BV(bvA0, Bs, 0)      // prime bvA for tile 0 (waited at tile0 P0 LGKM0)

  // ---- main loop: 31 macro-iters = tiles 0..61 ----
  int kq = 128;           // k-elem offset of tile t+2
  #pragma unroll 1
  for (int g = 0; g < 31; ++g) {
    TILE(0, bvA0, bvA1, kq,      1, VMW(3))
    TILE(1, bvA1, bvA0, kq + 64, 1, VMW(3))
    kq += 128;
  }
  // ---- tile 62 (buf0): no staging; drain for tile 63 ----
  TILE(0, bvA0, bvA1, 0, 0, VMW(0))
  // ---- tile 63 (buf1): last, no bvA-next / no vmcnt ----
  {
    const unsigned short* Ac = As + 16384;
    const unsigned short* Bc = Bs + 8192;
    RD_AVA(Ac)
    BAR; LGKM0;
    MFMA8(0, av0, bvA1, 0)
    RD_BV(bvB, Bc, 1)
    BAR; LGKM0;
    MFMA8(0, av0, bvB, 1)
    RD_AVB(Ac)
    BAR; LGKM0;
    MFMA8(1, av1, bvB, 1)
    MFMA8(1, av1, bvA1, 0)
  }
#undef RD_AVA
#undef RD_AVB
#undef RD_BV
#undef MFMA8
#undef TILE

  // ---- fused epilogue: bias + relu + weight by adj[q_b][row] + reduce ----
  // Load the two adj rows needed for this col-block's batches (b0, b0+1).
  const int b0 = bn >> 6;
  {
    int bsel = tid >> 8;           // 0 or 1
    int rloc = tid & 255;
    adjw[bsel][rloc] = adj[(size_t)q_ids[b0 + bsel] * NN + bm + rloc];
  }
  __syncthreads();

  const int cr = (lane >> 4) * 4;
  const int cc = lane & 15;
  float ps[4];
  #pragma unroll
  for (int ni = 0; ni < 4; ++ni) {
    int colh = wn * 32 + (ni & 1) * 16 + cc;   // h index (col & 63)
    float bias = b1[colh];
    float s = 0.f;
    #pragma unroll
    for (int mi = 0; mi < 4; ++mi) {
      int rowl = wm * 32 + (mi & 1) * 16 + (mi >> 1) * 128 + cr;
      #pragma unroll
      for (int r = 0; r < 4; ++r) {
        float v = acc[mi][ni][r] + bias;
        v = v > 0.f ? v : 0.f;
        s += adjw[ni >> 1][rowl + r] * v;
      }
    }
    ps[ni] = s;
  }
  // reduce across fq groups (lanes differing in bits 4,5)
  #pragma unroll
  for (int ni = 0; ni < 4; ++ni) {
    ps[ni] += __shfl_xor(ps[ni], 16, 64);
    ps[ni] += __shfl_xor(ps[ni], 32, 64);
  }
  if (lane < 16) {
    #pragma unroll
    for (int ni = 0; ni < 4; ++ni)
      red[wm * 2 + wn][ni * 16 + cc] = ps[ni];
  }
  __syncthreads();
  if (tid < 128) {
    int colLocal = tid;
    int wn2 = (colLocal >> 5) & 1;
    int ni2 = ((colLocal >> 6) << 1) | ((colLocal >> 4) & 1);
    int cc2 = colLocal & 15;
    float s = red[0 + wn2][ni2 * 16 + cc2] + red[2 + wn2][ni2 * 16 + cc2]
            + red[4 + wn2][ni2 * 16 + cc2] + red[6 + wn2][ni2 * 16 + cc2];
    partial[(size_t)blockIdx.x * NJ + bn + colLocal] = s;
  }
}

// ---------- K4: out[b][l] = sum_h (sum_rb partial[rb][b*64+h]) * W2[h][l] + b2[l] ----------
__global__ __launch_bounds__(1024) void k_out(const float* __restrict__ partial,
                                              const float* __restrict__ W2,
                                              const float* __restrict__ b2,
                                              float* __restrict__ out) {
  __shared__ float aggs[BATCH * FHID];   // 2048
  int t = threadIdx.x;
  for (int idx = t; idx < BATCH * FHID; idx += 1024) {
    float s = 0.f;
    #pragma unroll
    for (int c = 0; c < 16; ++c) s += partial[c * NJ + idx];
    aggs[idx] = s;
  }
  __syncthreads();
  int b = t >> 5, l = t & 31;
  float o = b2[l];
  #pragma unroll
  for (int h = 0; h < FHID; ++h) o += aggs[b * FHID + h] * W2[h * 32 + l];
  out[b * 32 + l] = o;
}

extern "C" void kernel_launch(void* const* d_in, const int* in_sizes, int n_in,
                              void* d_out, int out_size, void* d_ws, size_t ws_size,
                              hipStream_t stream) {
  const float* x   = (const float*)d_in[0];
  const int*   q   = (const int*)d_in[1];
  const float* adj = (const float*)d_in[2];
  const float* W1  = (const float*)d_in[3];
  const float* b1  = (const float*)d_in[4];
  const float* W2  = (const float*)d_in[5];
  const float* b2  = (const float*)d_in[6];
  float* out = (float*)d_out;

  char* ws = (char*)d_ws;
  unsigned short* adjb   = (unsigned short*)ws;                              // 32 MB
  unsigned short* St     = (unsigned short*)(ws + (size_t)32 * 1024 * 1024); // 16 MB
  float*          partial= (float*)(ws + (size_t)48 * 1024 * 1024);          // 128 KB

  // K0: adj -> bf16
  k_convert<<<(NN * NN / 4) / 256, 256, 0, stream>>>(adj, adjb);
  // K1: support^T via MFMA
  k_support<<<1024, 256, 0, stream>>>(x, W1, St);
  // K2: fused GEMM + bias/relu + row-weighted aggregation (no H buffer)
  dim3 g2(NN / 256, NJ / 128);
  k_gemm<<<g2, 512, 0, stream>>>(adjb, St, b1, adj, q, partial);
  // K3: reduce partials + final tiny GEMM
  k_out<<<1, 1024, 0, stream>>>(partial, W2, b2, out);
}